// Round 3
// baseline (250.524 us; speedup 1.0000x reference)
//
#include <hip/hip_runtime.h>
#include <hip/hip_bf16.h>
#include <math.h>

#define S 2048
#define CDIM 1024
#define H 256
#define HS 2048
#define E 16
#define GNUM 4
#define EPG 4
#define TOPK 4
#define KSLICES 8

typedef __attribute__((ext_vector_type(8))) short bfrag_t;   // 8 bf16 = 4 VGPRs
typedef __attribute__((ext_vector_type(4))) float facc_t;    // 4 fp32 acc
typedef __attribute__((ext_vector_type(4))) unsigned int u32x4;

__device__ __forceinline__ float sigmoidf_(float v) { return 1.f / (1.f + __expf(-v)); }

__device__ __forceinline__ unsigned short f2bf(float f) {
    union { float f; unsigned u; } v; v.f = f;
    unsigned r = v.u + 0x7FFFu + ((v.u >> 16) & 1u);   // round-to-nearest-even
    return (unsigned short)(r >> 16);
}
__device__ __forceinline__ float bf2f(unsigned short u) {
    union { unsigned u; float f; } v; v.u = ((unsigned)u) << 16; return v.f;
}
__device__ __forceinline__ unsigned long long pack4(float4 v) {
    return (unsigned long long)f2bf(v.x)
         | ((unsigned long long)f2bf(v.y) << 16)
         | ((unsigned long long)f2bf(v.z) << 32)
         | ((unsigned long long)f2bf(v.w) << 48);
}

// 16B/lane global->LDS DMA. LDS base is wave-uniform; lane L lands at l + L*16B.
__device__ __forceinline__ void stage16(const unsigned short* g, unsigned short* l, int lane) {
#if __has_builtin(__builtin_amdgcn_global_load_lds)
    __builtin_amdgcn_global_load_lds(
        (const __attribute__((address_space(1))) void*)g,
        (__attribute__((address_space(3))) void*)l, 16, 0, 0);
#else
    *(u32x4*)(l + lane * 8) = *(const u32x4*)g;
#endif
}

// ---------------------------------------------------------------------------
// K1a: split-K router logits + fused x->bf16 cast. Grid (S/16, 8).
// ---------------------------------------------------------------------------
__global__ __launch_bounds__(256) void logits_kernel(
    const float* __restrict__ x, const float* __restrict__ rw,
    float* __restrict__ lgpart, unsigned short* __restrict__ xb)
{
    const int ks = blockIdx.y;
    const int s0 = blockIdx.x * 16;
    const int tid = threadIdx.x;
    const int t = tid & 15, e = tid >> 4;
    const float4* xp = (const float4*)(x + (size_t)(s0 + t) * CDIM + ks * (CDIM / KSLICES));
    const float4* wp = (const float4*)(rw + (size_t)e * CDIM + ks * (CDIM / KSLICES));
    float acc = 0.f;
#pragma unroll 8
    for (int c = 0; c < CDIM / KSLICES / 4; ++c) {
        float4 xv = xp[c], wv = wp[c];
        acc += xv.x * wv.x + xv.y * wv.y + xv.z * wv.z + xv.w * wv.w;
    }
    float4 v0 = xp[e * 2], v1 = xp[e * 2 + 1];
    unsigned long long* dst = (unsigned long long*)
        (xb + (size_t)(s0 + t) * CDIM + ks * (CDIM / KSLICES) + e * 8);
    dst[0] = pack4(v0);
    dst[1] = pack4(v1);
    lgpart[((size_t)ks * S + s0 + t) * E + e] = acc;
}

// ---------------------------------------------------------------------------
// K1b: route one token per thread. Hierarchical compaction:
// LDS histogram -> one global atomicAdd per (block, expert) -> slot writes.
// ---------------------------------------------------------------------------
__global__ __launch_bounds__(256) void route_kernel(
    const float* __restrict__ lgpart, const float* __restrict__ bias,
    int* __restrict__ counts, int* __restrict__ list, float* __restrict__ wlist)
{
    __shared__ int lcount[E];
    __shared__ int lbase[E];
    const int tid = threadIdx.x;
    const int s = blockIdx.x * 256 + tid;
    if (tid < E) lcount[tid] = 0;
    float lgv[E];
#pragma unroll
    for (int i = 0; i < E; ++i) lgv[i] = 0.f;
#pragma unroll
    for (int ks = 0; ks < KSLICES; ++ks) {
        const float4* p = (const float4*)(lgpart + ((size_t)ks * S + s) * E);
#pragma unroll
        for (int q = 0; q < 4; ++q) {
            float4 v = p[q];
            lgv[q * 4 + 0] += v.x; lgv[q * 4 + 1] += v.y;
            lgv[q * 4 + 2] += v.z; lgv[q * 4 + 3] += v.w;
        }
    }
    float sc[E], sb[E];
#pragma unroll
    for (int e2 = 0; e2 < E; ++e2) {
        sc[e2] = 1.f / (1.f + __expf(-lgv[e2]));
        sb[e2] = sc[e2] + bias[e2];
    }
    float gsc[GNUM];
#pragma unroll
    for (int g = 0; g < GNUM; ++g) {
        int b_ = g * EPG;
        int m1 = 0; float v1 = sb[b_];
#pragma unroll
        for (int j = 1; j < EPG; ++j) if (sb[b_ + j] > v1) { v1 = sb[b_ + j]; m1 = j; }
        float v2 = -1e30f;
#pragma unroll
        for (int j = 0; j < EPG; ++j) if (j != m1 && sb[b_ + j] > v2) v2 = sb[b_ + j];
        gsc[g] = v1 + v2;
    }
    int g1 = 0;
#pragma unroll
    for (int g = 1; g < GNUM; ++g) if (gsc[g] > gsc[g1]) g1 = g;
    int g2 = (g1 == 0) ? 1 : 0;
#pragma unroll
    for (int g = 0; g < GNUM; ++g) if (g != g1 && gsc[g] > gsc[g2]) g2 = g;
    bool allowed[E];
#pragma unroll
    for (int e2 = 0; e2 < E; ++e2) {
        int g = e2 >> 2;
        allowed[e2] = (g == g1) || (g == g2);
    }
    int idx[TOPK]; float wk[TOPK];
#pragma unroll
    for (int k = 0; k < TOPK; ++k) {
        int best = 0; float bv = -1e30f;
#pragma unroll
        for (int e2 = 0; e2 < E; ++e2)
            if (allowed[e2] && sb[e2] > bv) { bv = sb[e2]; best = e2; }
        allowed[best] = false;
        idx[k] = best;
        wk[k] = sc[best];
    }
    float inv = 1.f / (wk[0] + wk[1] + wk[2] + wk[3] + 1e-20f);
    __syncthreads();            // lcount zero-init visible
    int lpos[TOPK];
#pragma unroll
    for (int k = 0; k < TOPK; ++k)
        lpos[k] = atomicAdd(&lcount[idx[k]], 1);   // LDS atomic (fast)
    __syncthreads();
    if (tid < E)
        lbase[tid] = atomicAdd(&counts[tid], lcount[tid]);  // 16 global atomics/block
    __syncthreads();
#pragma unroll
    for (int k = 0; k < TOPK; ++k) {
        int ee = idx[k];
        int pos = lbase[ee] + lpos[k];
        list[ee * S + pos] = s | (k << 16);
        wlist[ee * S + pos] = wk[k] * inv;
    }
}

// ---------------------------------------------------------------------------
// K2: merged fp32 -> bf16 cast of 3 equal-size (2M elem) weight buffers.
// ---------------------------------------------------------------------------
struct CastArgs {
    const float4* src[3];
    unsigned long long* dst[3];
};
__global__ __launch_bounds__(256) void cast_bf16_x3(CastArgs a, int n4)
{
    int i = blockIdx.x * 256 + threadIdx.x;
    if (i >= n4) return;
    const float4* src = a.src[blockIdx.y];
    a.dst[blockIdx.y][i] = pack4(src[i]);
}

// ---------------------------------------------------------------------------
// K3: tiled transpose + cast: src [z][R][Cc] fp32 -> dst [z][Cc][R] bf16.
// ---------------------------------------------------------------------------
__global__ __launch_bounds__(256) void transpose_cast2(
    const float* __restrict__ srcA, unsigned short* __restrict__ dstA,
    const float* __restrict__ srcB, unsigned short* __restrict__ dstB,
    int R, int Cc, int nz)
{
    __shared__ float t[32][33];
    int z = blockIdx.z;
    const float* src = (z < nz) ? srcA : srcB;
    unsigned short* dst = (z < nz) ? dstA : dstB;
    if (z >= nz) z -= nz;
    const size_t mo = (size_t)z * R * Cc;
    src += mo; dst += mo;
    const int c0 = blockIdx.x * 32, r0 = blockIdx.y * 32;
    const int tx = threadIdx.x, ty = threadIdx.y;  // (32, 8)
#pragma unroll
    for (int i = 0; i < 32; i += 8)
        t[ty + i][tx] = src[(size_t)(r0 + ty + i) * Cc + c0 + tx];
    __syncthreads();
#pragma unroll
    for (int i = 0; i < 32; i += 8)
        dst[(size_t)(c0 + ty + i) * R + r0 + tx] = f2bf(t[tx][ty + i]);
}

// ---------------------------------------------------------------------------
// MFMA GEMMs: 2-phase prefetch pipeline. Double-buffered LDS (BK=64 per
// buffer, two 32-wide halves). Per K-step: issue next tile's global_load_lds
// FIRST, then ds_read+MFMA on current tile, then ONE __syncthreads (its
// vmcnt/lgkm drain covers the prefetch + protects buffer reuse).
// ---------------------------------------------------------------------------

// K4: shared gate+up fused SwiGLU -> shb bf16 [S][HS]. BM=128/BN=64, BK=64.
// grid (HS/64=32, S/128=16). LDS 64 KB (2 blocks/CU; VGPR caps at 2 anyway).
__global__ __launch_bounds__(256) void gemm_shared_gateup(
    const unsigned short* __restrict__ xb, const unsigned short* __restrict__ gb,
    const unsigned short* __restrict__ ub, unsigned short* __restrict__ shb)
{
    // [buf][half][128*32] for A, [buf][half][64*32] for B
    __shared__ __align__(16) unsigned short As[2 * 2 * 128 * 32];
    __shared__ __align__(16) unsigned short Bg[2 * 2 * 64 * 32];
    __shared__ __align__(16) unsigned short Bu[2 * 2 * 64 * 32];
    const int tid = threadIdx.x;
    const int lane = tid & 63, w = tid >> 6;
    const int l15 = lane & 15, q = lane >> 4;
    const int r0 = blockIdx.y * 128;
    const int c0 = blockIdx.x * 64;
    const int wr = (w >> 1) * 64, wc = (w & 1) * 32;
    const int Lrow = lane >> 2;
    const int gseg = (lane & 3) ^ ((lane >> 3) & 3);
    const unsigned short* gA1 = xb + (size_t)(r0 + w * 16 + Lrow) * CDIM + gseg * 8;
    const unsigned short* gA2 = gA1 + (size_t)64 * CDIM;
    const unsigned short* gG  = gb + (size_t)(c0 + w * 16 + Lrow) * CDIM + gseg * 8;
    const unsigned short* gU  = ub + (size_t)(c0 + w * 16 + Lrow) * CDIM + gseg * 8;
    const int aoff = (w * 16) * 32;          // wave's staging slab offset
    const int swq = (q ^ ((l15 >> 1) & 3)) * 8;
    facc_t accg[4][2], accu[4][2];
#pragma unroll
    for (int i = 0; i < 4; ++i)
#pragma unroll
        for (int j = 0; j < 2; ++j) { accg[i][j] = 0.f; accu[i][j] = 0.f; }

#define K4_STAGE(B, K0)                                                         \
    {                                                                           \
        unsigned short* a0 = &As[(B) * 2 * 128 * 32 + aoff];                    \
        unsigned short* g0 = &Bg[(B) * 2 * 64 * 32 + aoff];                     \
        unsigned short* u0 = &Bu[(B) * 2 * 64 * 32 + aoff];                     \
        stage16(gA1 + (K0),      a0,                 lane);                      \
        stage16(gA1 + (K0) + 32, a0 + 128 * 32,      lane);                      \
        stage16(gA2 + (K0),      a0 + 64 * 32,       lane);                      \
        stage16(gA2 + (K0) + 32, a0 + 128 * 32 + 64 * 32, lane);                 \
        stage16(gG + (K0),       g0,                 lane);                      \
        stage16(gG + (K0) + 32,  g0 + 64 * 32,       lane);                      \
        stage16(gU + (K0),       u0,                 lane);                      \
        stage16(gU + (K0) + 32,  u0 + 64 * 32,       lane);                      \
    }

#define K4_COMPUTE(B)                                                           \
    _Pragma("unroll")                                                           \
    for (int kk = 0; kk < 2; ++kk) {                                            \
        const unsigned short* Ah = &As[(B) * 2 * 128 * 32 + kk * 128 * 32];     \
        const unsigned short* Gh = &Bg[(B) * 2 * 64 * 32 + kk * 64 * 32];       \
        const unsigned short* Uh = &Bu[(B) * 2 * 64 * 32 + kk * 64 * 32];       \
        bfrag_t af[4], gf[2], uf[2];                                            \
        _Pragma("unroll")                                                       \
        for (int i = 0; i < 4; ++i)                                             \
            af[i] = *(const bfrag_t*)&Ah[(wr + i * 16 + l15) * 32 + swq];       \
        _Pragma("unroll")                                                       \
        for (int j = 0; j < 2; ++j) {                                           \
            gf[j] = *(const bfrag_t*)&Gh[(wc + j * 16 + l15) * 32 + swq];       \
            uf[j] = *(const bfrag_t*)&Uh[(wc + j * 16 + l15) * 32 + swq];       \
        }                                                                       \
        _Pragma("unroll")                                                       \
        for (int i = 0; i < 4; ++i)                                             \
            _Pragma("unroll")                                                   \
            for (int j = 0; j < 2; ++j) {                                       \
                accg[i][j] = __builtin_amdgcn_mfma_f32_16x16x32_bf16(af[i], gf[j], accg[i][j], 0, 0, 0); \
                accu[i][j] = __builtin_amdgcn_mfma_f32_16x16x32_bf16(af[i], uf[j], accu[i][j], 0, 0, 0); \
            }                                                                   \
    }

    K4_STAGE(0, 0)
    __syncthreads();
    int cur = 0;
    for (int k0 = 64; k0 < CDIM; k0 += 64) {
        K4_STAGE(cur ^ 1, k0)      // prefetch next tile (flies during MFMA)
        K4_COMPUTE(cur)
        __syncthreads();           // drains prefetch + protects buffer reuse
        cur ^= 1;
    }
    K4_COMPUTE(cur)
#undef K4_STAGE
#undef K4_COMPUTE

#pragma unroll
    for (int i = 0; i < 4; ++i)
#pragma unroll
        for (int j = 0; j < 2; ++j)
#pragma unroll
            for (int r = 0; r < 4; ++r) {
                int row = r0 + wr + i * 16 + q * 4 + r;
                int col = c0 + wc + j * 16 + l15;
                float g = accg[i][j][r], u = accu[i][j][r];
                shb[(size_t)row * HS + col] = f2bf(g * sigmoidf_(g) * u);
            }
}

// K5: shared down-proj + routed-sum epilogue -> out fp32 [S][CDIM].
// BM=64/BN=64, BK=64, K=HS. grid (CDIM/64=16, S/64=32). RUNS LAST. LDS 32 KB.
__global__ __launch_bounds__(256) void gemm_shared_down(
    const unsigned short* __restrict__ shb, const unsigned short* __restrict__ db,
    const unsigned short* __restrict__ dbuf, float* __restrict__ out)
{
    __shared__ __align__(16) unsigned short As[2 * 2 * 64 * 32];
    __shared__ __align__(16) unsigned short Bs[2 * 2 * 64 * 32];
    const int tid = threadIdx.x;
    const int lane = tid & 63, w = tid >> 6;
    const int l15 = lane & 15, q = lane >> 4;
    const int r0 = blockIdx.y * 64;
    const int c0 = blockIdx.x * 64;
    const int wr = (w >> 1) * 32, wc = (w & 1) * 32;
    const int Lrow = lane >> 2;
    const int gseg = (lane & 3) ^ ((lane >> 3) & 3);
    const unsigned short* gA = shb + (size_t)(r0 + w * 16 + Lrow) * HS + gseg * 8;
    const unsigned short* gB = db + (size_t)(c0 + w * 16 + Lrow) * HS + gseg * 8;
    const int aoff = (w * 16) * 32;
    const int swq = (q ^ ((l15 >> 1) & 3)) * 8;
    facc_t acc[2][2];
#pragma unroll
    for (int i = 0; i < 2; ++i)
#pragma unroll
        for (int j = 0; j < 2; ++j) acc[i][j] = 0.f;

#define K5_STAGE(B, K0)                                                         \
    {                                                                           \
        unsigned short* a0 = &As[(B) * 2 * 64 * 32 + aoff];                     \
        unsigned short* b0 = &Bs[(B) * 2 * 64 * 32 + aoff];                     \
        stage16(gA + (K0),      a0,            lane);                           \
        stage16(gA + (K0) + 32, a0 + 64 * 32,  lane);                           \
        stage16(gB + (K0),      b0,            lane);                           \
        stage16(gB + (K0) + 32, b0 + 64 * 32,  lane);                           \
    }

#define K5_COMPUTE(B)                                                           \
    _Pragma("unroll")                                                           \
    for (int kk = 0; kk < 2; ++kk) {                                            \
        const unsigned short* Ah = &As[(B) * 2 * 64 * 32 + kk * 64 * 32];       \
        const unsigned short* Bh = &Bs[(B) * 2 * 64 * 32 + kk * 64 * 32];       \
        bfrag_t af[2], bf[2];                                                   \
        _Pragma("unroll")                                                       \
        for (int i = 0; i < 2; ++i) af[i] = *(const bfrag_t*)&Ah[(wr + i * 16 + l15) * 32 + swq]; \
        _Pragma("unroll")                                                       \
        for (int j = 0; j < 2; ++j) bf[j] = *(const bfrag_t*)&Bh[(wc + j * 16 + l15) * 32 + swq]; \
        _Pragma("unroll")                                                       \
        for (int i = 0; i < 2; ++i)                                             \
            _Pragma("unroll")                                                   \
            for (int j = 0; j < 2; ++j)                                         \
                acc[i][j] = __builtin_amdgcn_mfma_f32_16x16x32_bf16(af[i], bf[j], acc[i][j], 0, 0, 0); \
    }

    K5_STAGE(0, 0)
    __syncthreads();
    int cur = 0;
    for (int k0 = 64; k0 < HS; k0 += 64) {
        K5_STAGE(cur ^ 1, k0)
        K5_COMPUTE(cur)
        __syncthreads();
        cur ^= 1;
    }
    K5_COMPUTE(cur)
#undef K5_STAGE
#undef K5_COMPUTE

#pragma unroll
    for (int i = 0; i < 2; ++i)
#pragma unroll
        for (int j = 0; j < 2; ++j)
#pragma unroll
            for (int r = 0; r < 4; ++r) {
                int row = r0 + wr + i * 16 + q * 4 + r;
                int col = c0 + wc + j * 16 + l15;
                float v = acc[i][j][r];
                const unsigned short* dp = dbuf + ((size_t)row * TOPK) * CDIM + col;
#pragma unroll
                for (int k = 0; k < TOPK; ++k) v += bf2f(dp[(size_t)k * CDIM]);
                out[(size_t)row * CDIM + col] = v;
            }
}

// K6: routed gate+up, gathered A rows, weighted SwiGLU -> hbuf bf16 [S*4][H].
// BM=64/BN=64, BK=64. grid (E, H/64=4, S/64=32). LDS 48 KB.
__global__ __launch_bounds__(256) void gemm_routed_gateup(
    const unsigned short* __restrict__ xb, const unsigned short* __restrict__ gwT,
    const unsigned short* __restrict__ uwT, const int* __restrict__ counts,
    const int* __restrict__ list, const float* __restrict__ wlist,
    unsigned short* __restrict__ hbuf)
{
    const int e = blockIdx.x;
    const int n = counts[e];
    const int t0 = blockIdx.z * 64;
    if (t0 >= n) return;
    const int h0 = blockIdx.y * 64;
    __shared__ int toks[64];
    __shared__ int hrw[64];
    __shared__ float wv[64];
    __shared__ __align__(16) unsigned short As[2 * 2 * 64 * 32];
    __shared__ __align__(16) unsigned short Bg[2 * 2 * 64 * 32];
    __shared__ __align__(16) unsigned short Bu[2 * 2 * 64 * 32];
    const int tid = threadIdx.x;
    if (tid < 64) {
        int p = t0 + tid;
        if (p < n) {
            int pk = list[e * S + p];
            toks[tid] = pk & 0xFFFF;
            hrw[tid] = (pk & 0xFFFF) * TOPK + (pk >> 16);
            wv[tid] = wlist[e * S + p];
        } else { toks[tid] = 0; hrw[tid] = 0; wv[tid] = 0.f; }
    }
    __syncthreads();
    const int lane = tid & 63, w = tid >> 6;
    const int l15 = lane & 15, q = lane >> 4;
    const int wr = (w >> 1) * 32, wc = (w & 1) * 32;
    const int Lrow = lane >> 2;
    const int gseg = (lane & 3) ^ ((lane >> 3) & 3);
    const int tokA = toks[w * 16 + Lrow];        // per-lane gathered A row
    const unsigned short* gA = xb + (size_t)tokA * CDIM + gseg * 8;
    const unsigned short* gG = gwT + ((size_t)e * H + h0 + w * 16 + Lrow) * CDIM + gseg * 8;
    const unsigned short* gU = uwT + ((size_t)e * H + h0 + w * 16 + Lrow) * CDIM + gseg * 8;
    const int aoff = (w * 16) * 32;
    const int swq = (q ^ ((l15 >> 1) & 3)) * 8;
    facc_t accg[2][2], accu[2][2];
#pragma unroll
    for (int i = 0; i < 2; ++i)
#pragma unroll
        for (int j = 0; j < 2; ++j) { accg[i][j] = 0.f; accu[i][j] = 0.f; }

#define K6_STAGE(B, K0)                                                         \
    {                                                                           \
        unsigned short* a0 = &As[(B) * 2 * 64 * 32 + aoff];                     \
        unsigned short* g0 = &Bg[(B) * 2 * 64 * 32 + aoff];                     \
        unsigned short* u0 = &Bu[(B) * 2 * 64 * 32 + aoff];                     \
        stage16(gA + (K0),      a0,            lane);                           \
        stage16(gA + (K0) + 32, a0 + 64 * 32,  lane);                           \
        stage16(gG + (K0),      g0,            lane);                           \
        stage16(gG + (K0) + 32, g0 + 64 * 32,  lane);                           \
        stage16(gU + (K0),      u0,            lane);                           \
        stage16(gU + (K0) + 32, u0 + 64 * 32,  lane);                           \
    }

#define K6_COMPUTE(B)                                                           \
    _Pragma("unroll")                                                           \
    for (int kk = 0; kk < 2; ++kk) {                                            \
        const unsigned short* Ah = &As[(B) * 2 * 64 * 32 + kk * 64 * 32];       \
        const unsigned short* Gh = &Bg[(B) * 2 * 64 * 32 + kk * 64 * 32];       \
        const unsigned short* Uh = &Bu[(B) * 2 * 64 * 32 + kk * 64 * 32];       \
        bfrag_t af[2], gf[2], uf[2];                                            \
        _Pragma("unroll")                                                       \
        for (int i = 0; i < 2; ++i) af[i] = *(const bfrag_t*)&Ah[(wr + i * 16 + l15) * 32 + swq]; \
        _Pragma("unroll")                                                       \
        for (int j = 0; j < 2; ++j) {                                           \
            gf[j] = *(const bfrag_t*)&Gh[(wc + j * 16 + l15) * 32 + swq];       \
            uf[j] = *(const bfrag_t*)&Uh[(wc + j * 16 + l15) * 32 + swq];       \
        }                                                                       \
        _Pragma("unroll")                                                       \
        for (int i = 0; i < 2; ++i)                                             \
            _Pragma("unroll")                                                   \
            for (int j = 0; j < 2; ++j) {                                       \
                accg[i][j] = __builtin_amdgcn_mfma_f32_16x16x32_bf16(af[i], gf[j], accg[i][j], 0, 0, 0); \
                accu[i][j] = __builtin_amdgcn_mfma_f32_16x16x32_bf16(af[i], uf[j], accu[i][j], 0, 0, 0); \
            }                                                                   \
    }

    K6_STAGE(0, 0)
    __syncthreads();
    int cur = 0;
    for (int k0 = 64; k0 < CDIM; k0 += 64) {
        K6_STAGE(cur ^ 1, k0)
        K6_COMPUTE(cur)
        __syncthreads();
        cur ^= 1;
    }
    K6_COMPUTE(cur)
#undef K6_STAGE
#undef K6_COMPUTE

#pragma unroll
    for (int i = 0; i < 2; ++i)
#pragma unroll
        for (int j = 0; j < 2; ++j)
#pragma unroll
            for (int r = 0; r < 4; ++r) {
                int li = wr + i * 16 + q * 4 + r;
                if (t0 + li < n) {
                    int col = h0 + wc + j * 16 + l15;
                    float g = accg[i][j][r], u = accu[i][j][r];
                    hbuf[(size_t)hrw[li] * H + col] = f2bf(wv[li] * g * sigmoidf_(g) * u);
                }
            }
}

// K7: routed down-proj -> dbuf bf16 [S*4][CDIM]. BM=64/BN=64, BK=64, K=H=256.
// grid (E, CDIM/64=16, S/64=32). LDS 32 KB.
__global__ __launch_bounds__(256) void gemm_routed_down(
    const unsigned short* __restrict__ hbuf, const unsigned short* __restrict__ dwT,
    const int* __restrict__ counts, const int* __restrict__ list,
    unsigned short* __restrict__ dbuf)
{
    const int e = blockIdx.x;
    const int n = counts[e];
    const int t0 = blockIdx.z * 64;
    if (t0 >= n) return;
    const int c0 = blockIdx.y * 64;
    __shared__ int hrw[64];
    __shared__ __align__(16) unsigned short As[2 * 2 * 64 * 32];
    __shared__ __align__(16) unsigned short Bs[2 * 2 * 64 * 32];
    const int tid = threadIdx.x;
    if (tid < 64) {
        int p = t0 + tid;
        int pk = (p < n) ? list[e * S + p] : 0;
        hrw[tid] = (pk & 0xFFFF) * TOPK + (pk >> 16);
    }
    __syncthreads();
    const int lane = tid & 63, w = tid >> 6;
    const int l15 = lane & 15, q = lane >> 4;
    const int wr = (w >> 1) * 32, wc = (w & 1) * 32;
    const int Lrow = lane >> 2;
    const int gseg = (lane & 3) ^ ((lane >> 3) & 3);
    const int arow = hrw[w * 16 + Lrow];
    const unsigned short* gA = hbuf + (size_t)arow * H + gseg * 8;
    const unsigned short* gB = dwT + ((size_t)e * CDIM + c0 + w * 16 + Lrow) * H + gseg * 8;
    const int aoff = (w * 16) * 32;
    const int swq = (q ^ ((l15 >> 1) & 3)) * 8;
    facc_t acc[2][2];
#pragma unroll
    for (int i = 0; i < 2; ++i)
#pragma unroll
        for (int j = 0; j < 2; ++j) acc[i][j] = 0.f;

#define K7_STAGE(B, K0)                                                         \
    {                                                                           \
        unsigned short* a0 = &As[(B) * 2 * 64 * 32 + aoff];                     \
        unsigned short* b0 = &Bs[(B) * 2 * 64 * 32 + aoff];                     \
        stage16(gA + (K0),      a0,            lane);                           \
        stage16(gA + (K0) + 32, a0 + 64 * 32,  lane);                           \
        stage16(gB + (K0),      b0,            lane);                           \
        stage16(gB + (K0) + 32, b0 + 64 * 32,  lane);                           \
    }

#define K7_COMPUTE(B)                                                           \
    _Pragma("unroll")                                                           \
    for (int kk = 0; kk < 2; ++kk) {                                            \
        const unsigned short* Ah = &As[(B) * 2 * 64 * 32 + kk * 64 * 32];       \
        const unsigned short* Bh = &Bs[(B) * 2 * 64 * 32 + kk * 64 * 32];       \
        bfrag_t af[2], bf[2];                                                   \
        _Pragma("unroll")                                                       \
        for (int i = 0; i < 2; ++i) af[i] = *(const bfrag_t*)&Ah[(wr + i * 16 + l15) * 32 + swq]; \
        _Pragma("unroll")                                                       \
        for (int j = 0; j < 2; ++j) bf[j] = *(const bfrag_t*)&Bh[(wc + j * 16 + l15) * 32 + swq]; \
        _Pragma("unroll")                                                       \
        for (int i = 0; i < 2; ++i)                                             \
            _Pragma("unroll")                                                   \
            for (int j = 0; j < 2; ++j)                                         \
                acc[i][j] = __builtin_amdgcn_mfma_f32_16x16x32_bf16(af[i], bf[j], acc[i][j], 0, 0, 0); \
    }

    K7_STAGE(0, 0)
    __syncthreads();
    int cur = 0;
    for (int k0 = 64; k0 < H; k0 += 64) {
        K7_STAGE(cur ^ 1, k0)
        K7_COMPUTE(cur)
        __syncthreads();
        cur ^= 1;
    }
    K7_COMPUTE(cur)
#undef K7_STAGE
#undef K7_COMPUTE

#pragma unroll
    for (int i = 0; i < 2; ++i)
#pragma unroll
        for (int j = 0; j < 2; ++j)
#pragma unroll
            for (int r = 0; r < 4; ++r) {
                int li = wr + i * 16 + q * 4 + r;
                if (t0 + li < n) {
                    int col = c0 + wc + j * 16 + l15;
                    dbuf[(size_t)hrw[li] * CDIM + col] = f2bf(acc[i][j][r]);
                }
            }
}

// ---------------------------------------------------------------------------
extern "C" void kernel_launch(void* const* d_in, const int* in_sizes, int n_in,
                              void* d_out, int out_size, void* d_ws, size_t ws_size,
                              hipStream_t stream)
{
    const float* x        = (const float*)d_in[0];
    const float* router_w = (const float*)d_in[1];
    const float* bias     = (const float*)d_in[2];
    const float* gate_w   = (const float*)d_in[3];
    const float* up_w     = (const float*)d_in[4];
    const float* down_w   = (const float*)d_in[5];
    const float* sgw      = (const float*)d_in[6];
    const float* suw      = (const float*)d_in[7];
    const float* sdw      = (const float*)d_in[8];
    float* out = (float*)d_out;

    char* ws = (char*)d_ws;
    size_t off = 0;
    int* counts = (int*)(ws + off);            off += 256;
    int* list   = (int*)(ws + off);            off += (size_t)E * S * 4;
    float* wlist = (float*)(ws + off);         off += (size_t)E * S * 4;
    unsigned short* xb  = (unsigned short*)(ws + off); off += (size_t)S * CDIM * 2;
    unsigned short* sgb = (unsigned short*)(ws + off); off += (size_t)HS * CDIM * 2;
    unsigned short* sub = (unsigned short*)(ws + off); off += (size_t)HS * CDIM * 2;
    unsigned short* sdb = (unsigned short*)(ws + off); off += (size_t)CDIM * HS * 2;
    unsigned short* gwT = (unsigned short*)(ws + off); off += (size_t)E * H * CDIM * 2;
    unsigned short* uwT = (unsigned short*)(ws + off); off += (size_t)E * H * CDIM * 2;
    unsigned short* dwT = (unsigned short*)(ws + off); off += (size_t)E * CDIM * H * 2;
    unsigned short* shb = (unsigned short*)(ws + off); off += (size_t)S * HS * 2;
    unsigned short* hbuf = (unsigned short*)(ws + off); off += (size_t)S * TOPK * H * 2;
    unsigned short* dbuf = (unsigned short*)(ws + off); off += (size_t)S * TOPK * CDIM * 2;
    // lgpart (8*S*E floats = 1 MiB) aliases dbuf (consumed by route_kernel
    // before gemm_routed_down writes dbuf; same stream, serial).
    float* lgpart = (float*)dbuf;

    hipMemsetAsync(counts, 0, E * sizeof(int), stream);
    logits_kernel<<<dim3(S / 16, KSLICES), 256, 0, stream>>>(x, router_w, lgpart, xb);
    route_kernel<<<S / 256, 256, 0, stream>>>(lgpart, bias, counts, list, wlist);

    CastArgs ca;
    ca.src[0] = (const float4*)sgw; ca.dst[0] = (unsigned long long*)sgb;
    ca.src[1] = (const float4*)suw; ca.dst[1] = (unsigned long long*)sub;
    ca.src[2] = (const float4*)sdw; ca.dst[2] = (unsigned long long*)sdb;
    cast_bf16_x3<<<dim3(HS * CDIM / 4 / 256, 3), 256, 0, stream>>>(ca, HS * CDIM / 4);

    transpose_cast2<<<dim3(H / 32, CDIM / 32, 2 * E), dim3(32, 8), 0, stream>>>(
        gate_w, gwT, up_w, uwT, CDIM, H, E);
    transpose_cast2<<<dim3(CDIM / 32, H / 32, E), dim3(32, 8), 0, stream>>>(
        down_w, dwT, down_w, dwT, H, CDIM, E);

    gemm_shared_gateup<<<dim3(HS / 64, S / 128), 256, 0, stream>>>(xb, sgb, sub, shb);
    gemm_routed_gateup<<<dim3(E, H / 64, S / 64), 256, 0, stream>>>(xb, gwT, uwT, counts, list, wlist, hbuf);
    gemm_routed_down<<<dim3(E, CDIM / 64, S / 64), 256, 0, stream>>>(hbuf, dwT, counts, list, dbuf);
    // LAST: shared down-proj with fused routed-sum epilogue (reads dbuf).
    gemm_shared_down<<<dim3(CDIM / 64, S / 64), 256, 0, stream>>>(shb, sdb, dbuf, out);
}

// Round 4
// 228.375 us; speedup vs baseline: 1.0970x; 1.0970x over previous
//
#include <hip/hip_runtime.h>
#include <hip/hip_bf16.h>
#include <math.h>

#define S 2048
#define CDIM 1024
#define H 256
#define HS 2048
#define E 16
#define GNUM 4
#define EPG 4
#define TOPK 4
#define KSLICES 8

typedef __attribute__((ext_vector_type(8))) short bfrag_t;   // 8 bf16 = 4 VGPRs
typedef __attribute__((ext_vector_type(4))) float facc_t;    // 4 fp32 acc
typedef __attribute__((ext_vector_type(4))) unsigned int u32x4;

__device__ __forceinline__ float sigmoidf_(float v) { return 1.f / (1.f + __expf(-v)); }

__device__ __forceinline__ unsigned short f2bf(float f) {
    union { float f; unsigned u; } v; v.f = f;
    unsigned r = v.u + 0x7FFFu + ((v.u >> 16) & 1u);   // round-to-nearest-even
    return (unsigned short)(r >> 16);
}
__device__ __forceinline__ float bf2f(unsigned short u) {
    union { unsigned u; float f; } v; v.u = ((unsigned)u) << 16; return v.f;
}
__device__ __forceinline__ unsigned long long pack4(float4 v) {
    return (unsigned long long)f2bf(v.x)
         | ((unsigned long long)f2bf(v.y) << 16)
         | ((unsigned long long)f2bf(v.z) << 32)
         | ((unsigned long long)f2bf(v.w) << 48);
}

// 16B/lane global->LDS DMA. LDS base is wave-uniform; lane L lands at l + L*16B.
__device__ __forceinline__ void stage16(const unsigned short* g, unsigned short* l, int lane) {
#if __has_builtin(__builtin_amdgcn_global_load_lds)
    __builtin_amdgcn_global_load_lds(
        (const __attribute__((address_space(1))) void*)g,
        (__attribute__((address_space(3))) void*)l, 16, 0, 0);
#else
    *(u32x4*)(l + lane * 8) = *(const u32x4*)g;
#endif
}

struct CastArgs {
    const float4* src[3];
    unsigned long long* dst[3];
};

// ---------------------------------------------------------------------------
// PREPROC mega-kernel: one launch fuses four independent memory-bound passes
// (flat-grid partitioned; all 256-thread blocks):
//   [0, 1024)          : split-K router logits + fused x->bf16 cast
//   [1024, 7168)       : fp32->bf16 cast of 3 shared-weight buffers
//   [7168, 15360)      : transpose+cast gate_w/up_w  [E][C][H] -> [E][H][C]
//   [15360, 19456)     : transpose+cast down_w       [E][H][C] -> [E][C][H]
// Fusing removes 3 launch gaps and lets ramps/tails of the 4 ops overlap.
// ---------------------------------------------------------------------------
#define LG_BLOCKS   ((S / 16) * KSLICES)                    // 1024
#define CAST_BLOCKS (3 * (HS * CDIM / 4 / 256))             // 6144
#define TGU_BLOCKS  (2 * E * (CDIM / 32) * (H / 32))        // 8192
#define TDN_BLOCKS  (E * (H / 32) * (CDIM / 32))            // 4096

__global__ __launch_bounds__(256) void preproc_kernel(
    const float* __restrict__ x, const float* __restrict__ rw,
    float* __restrict__ lgpart, unsigned short* __restrict__ xb,
    CastArgs ca,
    const float* __restrict__ gate_w, unsigned short* __restrict__ gwT,
    const float* __restrict__ up_w,  unsigned short* __restrict__ uwT,
    const float* __restrict__ down_w, unsigned short* __restrict__ dwT)
{
    __shared__ float tbuf[32][33];
    const int tid = threadIdx.x;
    int id = blockIdx.x;

    if (id < LG_BLOCKS) {
        // ---- logits + x cast (grid was (S/16=128, KSLICES=8)) ----
        const int ks = id >> 7;
        const int s0 = (id & 127) * 16;
        const int t = tid & 15, e = tid >> 4;
        const float4* xp = (const float4*)(x + (size_t)(s0 + t) * CDIM + ks * (CDIM / KSLICES));
        const float4* wp = (const float4*)(rw + (size_t)e * CDIM + ks * (CDIM / KSLICES));
        float acc = 0.f;
#pragma unroll 8
        for (int c = 0; c < CDIM / KSLICES / 4; ++c) {
            float4 xv = xp[c], wv = wp[c];
            acc += xv.x * wv.x + xv.y * wv.y + xv.z * wv.z + xv.w * wv.w;
        }
        float4 v0 = xp[e * 2], v1 = xp[e * 2 + 1];
        unsigned long long* dst = (unsigned long long*)
            (xb + (size_t)(s0 + t) * CDIM + ks * (CDIM / KSLICES) + e * 8);
        dst[0] = pack4(v0);
        dst[1] = pack4(v1);
        lgpart[((size_t)ks * S + s0 + t) * E + e] = acc;
        return;
    }
    id -= LG_BLOCKS;

    if (id < CAST_BLOCKS) {
        // ---- shared-weight casts (3 bufs x 2048 blocks) ----
        const int buf = id >> 11;
        const int i = (id & 2047) * 256 + tid;
        ca.dst[buf][i] = pack4(ca.src[buf][i]);
        return;
    }
    id -= CAST_BLOCKS;

    // ---- transposes ----
    const float* src; unsigned short* dst; int R, Cc, zz, c0, r0;
    if (id < TGU_BLOCKS) {
        // gate/up: x in [0,8) (H/32), y in [0,32) (CDIM/32), z in [0,32) (2E)
        const int bx = id & 7; int rem = id >> 3;
        const int by = rem & 31; const int bz = rem >> 5;
        R = CDIM; Cc = H;
        src = (bz < E) ? gate_w : up_w;
        dst = (bz < E) ? gwT : uwT;
        zz = (bz < E) ? bz : bz - E;
        c0 = bx * 32; r0 = by * 32;
    } else {
        id -= TGU_BLOCKS;
        // down: x in [0,32) (CDIM/32), y in [0,8) (H/32), z in [0,16) (E)
        const int bx = id & 31; int rem = id >> 5;
        const int by = rem & 7; const int bz = rem >> 3;
        R = H; Cc = CDIM;
        src = down_w; dst = dwT; zz = bz;
        c0 = bx * 32; r0 = by * 32;
    }
    const size_t mo = (size_t)zz * R * Cc;
    src += mo; dst += mo;
    const int tx = tid & 31, ty = tid >> 5;   // (32, 8)
#pragma unroll
    for (int i = 0; i < 32; i += 8)
        tbuf[ty + i][tx] = src[(size_t)(r0 + ty + i) * Cc + c0 + tx];
    __syncthreads();
#pragma unroll
    for (int i = 0; i < 32; i += 8)
        dst[(size_t)(c0 + ty + i) * R + r0 + tx] = f2bf(tbuf[tx][ty + i]);
}

// ---------------------------------------------------------------------------
// K1b: route one token per thread. Hierarchical compaction:
// LDS histogram -> one global atomicAdd per (block, expert) -> slot writes.
// ---------------------------------------------------------------------------
__global__ __launch_bounds__(256) void route_kernel(
    const float* __restrict__ lgpart, const float* __restrict__ bias,
    int* __restrict__ counts, int* __restrict__ list, float* __restrict__ wlist)
{
    __shared__ int lcount[E];
    __shared__ int lbase[E];
    const int tid = threadIdx.x;
    const int s = blockIdx.x * 256 + tid;
    if (tid < E) lcount[tid] = 0;
    float lgv[E];
#pragma unroll
    for (int i = 0; i < E; ++i) lgv[i] = 0.f;
#pragma unroll
    for (int ks = 0; ks < KSLICES; ++ks) {
        const float4* p = (const float4*)(lgpart + ((size_t)ks * S + s) * E);
#pragma unroll
        for (int q = 0; q < 4; ++q) {
            float4 v = p[q];
            lgv[q * 4 + 0] += v.x; lgv[q * 4 + 1] += v.y;
            lgv[q * 4 + 2] += v.z; lgv[q * 4 + 3] += v.w;
        }
    }
    float sc[E], sb[E];
#pragma unroll
    for (int e2 = 0; e2 < E; ++e2) {
        sc[e2] = 1.f / (1.f + __expf(-lgv[e2]));
        sb[e2] = sc[e2] + bias[e2];
    }
    float gsc[GNUM];
#pragma unroll
    for (int g = 0; g < GNUM; ++g) {
        int b_ = g * EPG;
        int m1 = 0; float v1 = sb[b_];
#pragma unroll
        for (int j = 1; j < EPG; ++j) if (sb[b_ + j] > v1) { v1 = sb[b_ + j]; m1 = j; }
        float v2 = -1e30f;
#pragma unroll
        for (int j = 0; j < EPG; ++j) if (j != m1 && sb[b_ + j] > v2) v2 = sb[b_ + j];
        gsc[g] = v1 + v2;
    }
    int g1 = 0;
#pragma unroll
    for (int g = 1; g < GNUM; ++g) if (gsc[g] > gsc[g1]) g1 = g;
    int g2 = (g1 == 0) ? 1 : 0;
#pragma unroll
    for (int g = 0; g < GNUM; ++g) if (g != g1 && gsc[g] > gsc[g2]) g2 = g;
    bool allowed[E];
#pragma unroll
    for (int e2 = 0; e2 < E; ++e2) {
        int g = e2 >> 2;
        allowed[e2] = (g == g1) || (g == g2);
    }
    int idx[TOPK]; float wk[TOPK];
#pragma unroll
    for (int k = 0; k < TOPK; ++k) {
        int best = 0; float bv = -1e30f;
#pragma unroll
        for (int e2 = 0; e2 < E; ++e2)
            if (allowed[e2] && sb[e2] > bv) { bv = sb[e2]; best = e2; }
        allowed[best] = false;
        idx[k] = best;
        wk[k] = sc[best];
    }
    float inv = 1.f / (wk[0] + wk[1] + wk[2] + wk[3] + 1e-20f);
    __syncthreads();            // lcount zero-init visible
    int lpos[TOPK];
#pragma unroll
    for (int k = 0; k < TOPK; ++k)
        lpos[k] = atomicAdd(&lcount[idx[k]], 1);   // LDS atomic (fast)
    __syncthreads();
    if (tid < E)
        lbase[tid] = atomicAdd(&counts[tid], lcount[tid]);  // 16 global atomics/block
    __syncthreads();
#pragma unroll
    for (int k = 0; k < TOPK; ++k) {
        int ee = idx[k];
        int pos = lbase[ee] + lpos[k];
        list[ee * S + pos] = s | (k << 16);
        wlist[ee * S + pos] = wk[k] * inv;
    }
}

// ---------------------------------------------------------------------------
// m97-style MFMA GEMMs, BK=64 single-buffer (round-2 proven structure):
// two 32-wide k-halves stacked in LDS, 2 barriers per K-step.
// ---------------------------------------------------------------------------

// K4: shared gate+up fused SwiGLU -> shb bf16 [S][HS]. BM=128/BN=64, BK=64.
// grid (HS/64=32, S/128=16).
__global__ __launch_bounds__(256) void gemm_shared_gateup(
    const unsigned short* __restrict__ xb, const unsigned short* __restrict__ gb,
    const unsigned short* __restrict__ ub, unsigned short* __restrict__ shb)
{
    __shared__ __align__(16) unsigned short As[2 * 128 * 32];
    __shared__ __align__(16) unsigned short Bg[2 * 64 * 32];
    __shared__ __align__(16) unsigned short Bu[2 * 64 * 32];
    const int tid = threadIdx.x;
    const int lane = tid & 63, w = tid >> 6;
    const int l15 = lane & 15, q = lane >> 4;
    const int r0 = blockIdx.y * 128;
    const int c0 = blockIdx.x * 64;
    const int wr = (w >> 1) * 64, wc = (w & 1) * 32;
    const int Lrow = lane >> 2;
    const int gseg = (lane & 3) ^ ((lane >> 3) & 3);
    const unsigned short* gA1 = xb + (size_t)(r0 + w * 16 + Lrow) * CDIM + gseg * 8;
    const unsigned short* gA2 = gA1 + (size_t)64 * CDIM;
    const unsigned short* gG  = gb + (size_t)(c0 + w * 16 + Lrow) * CDIM + gseg * 8;
    const unsigned short* gU  = ub + (size_t)(c0 + w * 16 + Lrow) * CDIM + gseg * 8;
    unsigned short* lA1 = &As[(w * 16) * 32];
    unsigned short* lA2 = lA1 + 64 * 32;
    unsigned short* lG  = &Bg[(w * 16) * 32];
    unsigned short* lU  = &Bu[(w * 16) * 32];
    const int swq = (q ^ ((l15 >> 1) & 3)) * 8;
    facc_t accg[4][2], accu[4][2];
#pragma unroll
    for (int i = 0; i < 4; ++i)
#pragma unroll
        for (int j = 0; j < 2; ++j) { accg[i][j] = 0.f; accu[i][j] = 0.f; }
    for (int k0 = 0; k0 < CDIM; k0 += 64) {
        stage16(gA1 + k0,      lA1,             lane);
        stage16(gA1 + k0 + 32, lA1 + 128 * 32,  lane);
        stage16(gA2 + k0,      lA2,             lane);
        stage16(gA2 + k0 + 32, lA2 + 128 * 32,  lane);
        stage16(gG + k0,       lG,              lane);
        stage16(gG + k0 + 32,  lG + 64 * 32,    lane);
        stage16(gU + k0,       lU,              lane);
        stage16(gU + k0 + 32,  lU + 64 * 32,    lane);
        __syncthreads();
#pragma unroll
        for (int kk = 0; kk < 2; ++kk) {
            const unsigned short* Ah = &As[kk * 128 * 32];
            const unsigned short* Gh = &Bg[kk * 64 * 32];
            const unsigned short* Uh = &Bu[kk * 64 * 32];
            bfrag_t af[4], gf[2], uf[2];
#pragma unroll
            for (int i = 0; i < 4; ++i)
                af[i] = *(const bfrag_t*)&Ah[(wr + i * 16 + l15) * 32 + swq];
#pragma unroll
            for (int j = 0; j < 2; ++j) {
                gf[j] = *(const bfrag_t*)&Gh[(wc + j * 16 + l15) * 32 + swq];
                uf[j] = *(const bfrag_t*)&Uh[(wc + j * 16 + l15) * 32 + swq];
            }
#pragma unroll
            for (int i = 0; i < 4; ++i)
#pragma unroll
                for (int j = 0; j < 2; ++j) {
                    accg[i][j] = __builtin_amdgcn_mfma_f32_16x16x32_bf16(af[i], gf[j], accg[i][j], 0, 0, 0);
                    accu[i][j] = __builtin_amdgcn_mfma_f32_16x16x32_bf16(af[i], uf[j], accu[i][j], 0, 0, 0);
                }
        }
        __syncthreads();
    }
#pragma unroll
    for (int i = 0; i < 4; ++i)
#pragma unroll
        for (int j = 0; j < 2; ++j)
#pragma unroll
            for (int r = 0; r < 4; ++r) {
                int row = r0 + wr + i * 16 + q * 4 + r;
                int col = c0 + wc + j * 16 + l15;
                float g = accg[i][j][r], u = accu[i][j][r];
                shb[(size_t)row * HS + col] = f2bf(g * sigmoidf_(g) * u);
            }
}

// K5: shared down-proj + routed-sum epilogue -> out fp32 [S][CDIM].
// BM=64/BN=64, BK=64, K=HS. grid (CDIM/64=16, S/64=32). RUNS LAST.
__global__ __launch_bounds__(256) void gemm_shared_down(
    const unsigned short* __restrict__ shb, const unsigned short* __restrict__ db,
    const unsigned short* __restrict__ dbuf, float* __restrict__ out)
{
    __shared__ __align__(16) unsigned short As[2 * 64 * 32];
    __shared__ __align__(16) unsigned short Bs[2 * 64 * 32];
    const int tid = threadIdx.x;
    const int lane = tid & 63, w = tid >> 6;
    const int l15 = lane & 15, q = lane >> 4;
    const int r0 = blockIdx.y * 64;
    const int c0 = blockIdx.x * 64;
    const int wr = (w >> 1) * 32, wc = (w & 1) * 32;
    const int Lrow = lane >> 2;
    const int gseg = (lane & 3) ^ ((lane >> 3) & 3);
    const unsigned short* gA = shb + (size_t)(r0 + w * 16 + Lrow) * HS + gseg * 8;
    const unsigned short* gB = db + (size_t)(c0 + w * 16 + Lrow) * HS + gseg * 8;
    unsigned short* lA = &As[(w * 16) * 32];
    unsigned short* lB = &Bs[(w * 16) * 32];
    const int swq = (q ^ ((l15 >> 1) & 3)) * 8;
    facc_t acc[2][2];
#pragma unroll
    for (int i = 0; i < 2; ++i)
#pragma unroll
        for (int j = 0; j < 2; ++j) acc[i][j] = 0.f;
    for (int k0 = 0; k0 < HS; k0 += 64) {
        stage16(gA + k0,      lA,            lane);
        stage16(gA + k0 + 32, lA + 64 * 32,  lane);
        stage16(gB + k0,      lB,            lane);
        stage16(gB + k0 + 32, lB + 64 * 32,  lane);
        __syncthreads();
#pragma unroll
        for (int kk = 0; kk < 2; ++kk) {
            const unsigned short* Ah = &As[kk * 64 * 32];
            const unsigned short* Bh = &Bs[kk * 64 * 32];
            bfrag_t af[2], bf[2];
#pragma unroll
            for (int i = 0; i < 2; ++i) af[i] = *(const bfrag_t*)&Ah[(wr + i * 16 + l15) * 32 + swq];
#pragma unroll
            for (int j = 0; j < 2; ++j) bf[j] = *(const bfrag_t*)&Bh[(wc + j * 16 + l15) * 32 + swq];
#pragma unroll
            for (int i = 0; i < 2; ++i)
#pragma unroll
                for (int j = 0; j < 2; ++j)
                    acc[i][j] = __builtin_amdgcn_mfma_f32_16x16x32_bf16(af[i], bf[j], acc[i][j], 0, 0, 0);
        }
        __syncthreads();
    }
#pragma unroll
    for (int i = 0; i < 2; ++i)
#pragma unroll
        for (int j = 0; j < 2; ++j)
#pragma unroll
            for (int r = 0; r < 4; ++r) {
                int row = r0 + wr + i * 16 + q * 4 + r;
                int col = c0 + wc + j * 16 + l15;
                float v = acc[i][j][r];
                const unsigned short* dp = dbuf + ((size_t)row * TOPK) * CDIM + col;
#pragma unroll
                for (int k = 0; k < TOPK; ++k) v += bf2f(dp[(size_t)k * CDIM]);
                out[(size_t)row * CDIM + col] = v;
            }
}

// K6: routed gate+up, gathered A rows, weighted SwiGLU -> hbuf bf16 [S*4][H].
// BM=64/BN=64, BK=64. grid (E, H/64=4, S/64=32); expert-major for XCD L2.
__global__ __launch_bounds__(256) void gemm_routed_gateup(
    const unsigned short* __restrict__ xb, const unsigned short* __restrict__ gwT,
    const unsigned short* __restrict__ uwT, const int* __restrict__ counts,
    const int* __restrict__ list, const float* __restrict__ wlist,
    unsigned short* __restrict__ hbuf)
{
    const int e = blockIdx.x;
    const int n = counts[e];
    const int t0 = blockIdx.z * 64;
    if (t0 >= n) return;
    const int h0 = blockIdx.y * 64;
    __shared__ int toks[64];
    __shared__ int hrw[64];
    __shared__ float wv[64];
    __shared__ __align__(16) unsigned short As[2 * 64 * 32];
    __shared__ __align__(16) unsigned short Bg[2 * 64 * 32];
    __shared__ __align__(16) unsigned short Bu[2 * 64 * 32];
    const int tid = threadIdx.x;
    if (tid < 64) {
        int p = t0 + tid;
        if (p < n) {
            int pk = list[e * S + p];
            toks[tid] = pk & 0xFFFF;
            hrw[tid] = (pk & 0xFFFF) * TOPK + (pk >> 16);
            wv[tid] = wlist[e * S + p];
        } else { toks[tid] = 0; hrw[tid] = 0; wv[tid] = 0.f; }
    }
    __syncthreads();
    const int lane = tid & 63, w = tid >> 6;
    const int l15 = lane & 15, q = lane >> 4;
    const int wr = (w >> 1) * 32, wc = (w & 1) * 32;
    const int Lrow = lane >> 2;
    const int gseg = (lane & 3) ^ ((lane >> 3) & 3);
    const int tokA = toks[w * 16 + Lrow];        // per-lane gathered A row
    const unsigned short* gA = xb + (size_t)tokA * CDIM + gseg * 8;
    const unsigned short* gG = gwT + ((size_t)e * H + h0 + w * 16 + Lrow) * CDIM + gseg * 8;
    const unsigned short* gU = uwT + ((size_t)e * H + h0 + w * 16 + Lrow) * CDIM + gseg * 8;
    unsigned short* lA = &As[(w * 16) * 32];
    unsigned short* lG = &Bg[(w * 16) * 32];
    unsigned short* lU = &Bu[(w * 16) * 32];
    const int swq = (q ^ ((l15 >> 1) & 3)) * 8;
    facc_t accg[2][2], accu[2][2];
#pragma unroll
    for (int i = 0; i < 2; ++i)
#pragma unroll
        for (int j = 0; j < 2; ++j) { accg[i][j] = 0.f; accu[i][j] = 0.f; }
    for (int k0 = 0; k0 < CDIM; k0 += 64) {
        stage16(gA + k0,      lA,            lane);
        stage16(gA + k0 + 32, lA + 64 * 32,  lane);
        stage16(gG + k0,      lG,            lane);
        stage16(gG + k0 + 32, lG + 64 * 32,  lane);
        stage16(gU + k0,      lU,            lane);
        stage16(gU + k0 + 32, lU + 64 * 32,  lane);
        __syncthreads();
#pragma unroll
        for (int kk = 0; kk < 2; ++kk) {
            const unsigned short* Ah = &As[kk * 64 * 32];
            const unsigned short* Gh = &Bg[kk * 64 * 32];
            const unsigned short* Uh = &Bu[kk * 64 * 32];
            bfrag_t af[2], gf[2], uf[2];
#pragma unroll
            for (int i = 0; i < 2; ++i) af[i] = *(const bfrag_t*)&Ah[(wr + i * 16 + l15) * 32 + swq];
#pragma unroll
            for (int j = 0; j < 2; ++j) {
                gf[j] = *(const bfrag_t*)&Gh[(wc + j * 16 + l15) * 32 + swq];
                uf[j] = *(const bfrag_t*)&Uh[(wc + j * 16 + l15) * 32 + swq];
            }
#pragma unroll
            for (int i = 0; i < 2; ++i)
#pragma unroll
                for (int j = 0; j < 2; ++j) {
                    accg[i][j] = __builtin_amdgcn_mfma_f32_16x16x32_bf16(af[i], gf[j], accg[i][j], 0, 0, 0);
                    accu[i][j] = __builtin_amdgcn_mfma_f32_16x16x32_bf16(af[i], uf[j], accu[i][j], 0, 0, 0);
                }
        }
        __syncthreads();
    }
#pragma unroll
    for (int i = 0; i < 2; ++i)
#pragma unroll
        for (int j = 0; j < 2; ++j)
#pragma unroll
            for (int r = 0; r < 4; ++r) {
                int li = wr + i * 16 + q * 4 + r;
                if (t0 + li < n) {
                    int col = h0 + wc + j * 16 + l15;
                    float g = accg[i][j][r], u = accu[i][j][r];
                    hbuf[(size_t)hrw[li] * H + col] = f2bf(wv[li] * g * sigmoidf_(g) * u);
                }
            }
}

// K7: routed down-proj -> dbuf bf16 [S*4][CDIM]. BM=64/BN=64, BK=64, K=H=256.
// grid (E, CDIM/64=16, S/64=32); expert-major for XCD L2.
__global__ __launch_bounds__(256) void gemm_routed_down(
    const unsigned short* __restrict__ hbuf, const unsigned short* __restrict__ dwT,
    const int* __restrict__ counts, const int* __restrict__ list,
    unsigned short* __restrict__ dbuf)
{
    const int e = blockIdx.x;
    const int n = counts[e];
    const int t0 = blockIdx.z * 64;
    if (t0 >= n) return;
    const int c0 = blockIdx.y * 64;
    __shared__ int hrw[64];
    __shared__ __align__(16) unsigned short As[2 * 64 * 32];
    __shared__ __align__(16) unsigned short Bs[2 * 64 * 32];
    const int tid = threadIdx.x;
    if (tid < 64) {
        int p = t0 + tid;
        int pk = (p < n) ? list[e * S + p] : 0;
        hrw[tid] = (pk & 0xFFFF) * TOPK + (pk >> 16);
    }
    __syncthreads();
    const int lane = tid & 63, w = tid >> 6;
    const int l15 = lane & 15, q = lane >> 4;
    const int wr = (w >> 1) * 32, wc = (w & 1) * 32;
    const int Lrow = lane >> 2;
    const int gseg = (lane & 3) ^ ((lane >> 3) & 3);
    const int arow = hrw[w * 16 + Lrow];
    const unsigned short* gA = hbuf + (size_t)arow * H + gseg * 8;
    const unsigned short* gB = dwT + ((size_t)e * CDIM + c0 + w * 16 + Lrow) * H + gseg * 8;
    unsigned short* lA = &As[(w * 16) * 32];
    unsigned short* lB = &Bs[(w * 16) * 32];
    const int swq = (q ^ ((l15 >> 1) & 3)) * 8;
    facc_t acc[2][2];
#pragma unroll
    for (int i = 0; i < 2; ++i)
#pragma unroll
        for (int j = 0; j < 2; ++j) acc[i][j] = 0.f;
    for (int k0 = 0; k0 < H; k0 += 64) {
        stage16(gA + k0,      lA,            lane);
        stage16(gA + k0 + 32, lA + 64 * 32,  lane);
        stage16(gB + k0,      lB,            lane);
        stage16(gB + k0 + 32, lB + 64 * 32,  lane);
        __syncthreads();
#pragma unroll
        for (int kk = 0; kk < 2; ++kk) {
            const unsigned short* Ah = &As[kk * 64 * 32];
            const unsigned short* Bh = &Bs[kk * 64 * 32];
            bfrag_t af[2], bf[2];
#pragma unroll
            for (int i = 0; i < 2; ++i) af[i] = *(const bfrag_t*)&Ah[(wr + i * 16 + l15) * 32 + swq];
#pragma unroll
            for (int j = 0; j < 2; ++j) bf[j] = *(const bfrag_t*)&Bh[(wc + j * 16 + l15) * 32 + swq];
#pragma unroll
            for (int i = 0; i < 2; ++i)
#pragma unroll
                for (int j = 0; j < 2; ++j)
                    acc[i][j] = __builtin_amdgcn_mfma_f32_16x16x32_bf16(af[i], bf[j], acc[i][j], 0, 0, 0);
        }
        __syncthreads();
    }
#pragma unroll
    for (int i = 0; i < 2; ++i)
#pragma unroll
        for (int j = 0; j < 2; ++j)
#pragma unroll
            for (int r = 0; r < 4; ++r) {
                int li = wr + i * 16 + q * 4 + r;
                if (t0 + li < n) {
                    int col = c0 + wc + j * 16 + l15;
                    dbuf[(size_t)hrw[li] * CDIM + col] = f2bf(acc[i][j][r]);
                }
            }
}

// ---------------------------------------------------------------------------
extern "C" void kernel_launch(void* const* d_in, const int* in_sizes, int n_in,
                              void* d_out, int out_size, void* d_ws, size_t ws_size,
                              hipStream_t stream)
{
    const float* x        = (const float*)d_in[0];
    const float* router_w = (const float*)d_in[1];
    const float* bias     = (const float*)d_in[2];
    const float* gate_w   = (const float*)d_in[3];
    const float* up_w     = (const float*)d_in[4];
    const float* down_w   = (const float*)d_in[5];
    const float* sgw      = (const float*)d_in[6];
    const float* suw      = (const float*)d_in[7];
    const float* sdw      = (const float*)d_in[8];
    float* out = (float*)d_out;

    char* ws = (char*)d_ws;
    size_t off = 0;
    int* counts = (int*)(ws + off);            off += 256;
    int* list   = (int*)(ws + off);            off += (size_t)E * S * 4;
    float* wlist = (float*)(ws + off);         off += (size_t)E * S * 4;
    unsigned short* xb  = (unsigned short*)(ws + off); off += (size_t)S * CDIM * 2;
    unsigned short* sgb = (unsigned short*)(ws + off); off += (size_t)HS * CDIM * 2;
    unsigned short* sub = (unsigned short*)(ws + off); off += (size_t)HS * CDIM * 2;
    unsigned short* sdb = (unsigned short*)(ws + off); off += (size_t)CDIM * HS * 2;
    unsigned short* gwT = (unsigned short*)(ws + off); off += (size_t)E * H * CDIM * 2;
    unsigned short* uwT = (unsigned short*)(ws + off); off += (size_t)E * H * CDIM * 2;
    unsigned short* dwT = (unsigned short*)(ws + off); off += (size_t)E * CDIM * H * 2;
    unsigned short* shb = (unsigned short*)(ws + off); off += (size_t)S * HS * 2;
    unsigned short* hbuf = (unsigned short*)(ws + off); off += (size_t)S * TOPK * H * 2;
    unsigned short* dbuf = (unsigned short*)(ws + off); off += (size_t)S * TOPK * CDIM * 2;
    // lgpart (8*S*E floats = 1 MiB) aliases dbuf (consumed by route_kernel
    // before gemm_routed_down writes dbuf; same stream, serial).
    float* lgpart = (float*)dbuf;

    hipMemsetAsync(counts, 0, E * sizeof(int), stream);

    CastArgs ca;
    ca.src[0] = (const float4*)sgw; ca.dst[0] = (unsigned long long*)sgb;
    ca.src[1] = (const float4*)suw; ca.dst[1] = (unsigned long long*)sub;
    ca.src[2] = (const float4*)sdw; ca.dst[2] = (unsigned long long*)sdb;

    // One fused preprocessing launch: logits+xcast, weight casts, transposes.
    preproc_kernel<<<LG_BLOCKS + CAST_BLOCKS + TGU_BLOCKS + TDN_BLOCKS, 256, 0, stream>>>(
        x, router_w, lgpart, xb, ca, gate_w, gwT, up_w, uwT, down_w, dwT);

    route_kernel<<<S / 256, 256, 0, stream>>>(lgpart, bias, counts, list, wlist);

    gemm_shared_gateup<<<dim3(HS / 64, S / 128), 256, 0, stream>>>(xb, sgb, sub, shb);
    gemm_routed_gateup<<<dim3(E, H / 64, S / 64), 256, 0, stream>>>(xb, gwT, uwT, counts, list, wlist, hbuf);
    gemm_routed_down<<<dim3(E, CDIM / 64, S / 64), 256, 0, stream>>>(hbuf, dwT, counts, list, dbuf);
    // LAST: shared down-proj with fused routed-sum epilogue (reads dbuf).
    gemm_shared_down<<<dim3(CDIM / 64, S / 64), 256, 0, stream>>>(shb, sdb, dbuf, out);
}

// Round 5
// 226.675 us; speedup vs baseline: 1.1052x; 1.0075x over previous
//
#include <hip/hip_runtime.h>
#include <hip/hip_bf16.h>
#include <math.h>

#define S 2048
#define CDIM 1024
#define H 256
#define HS 2048
#define E 16
#define GNUM 4
#define EPG 4
#define TOPK 4
#define KSLICES 8

typedef __attribute__((ext_vector_type(8))) short bfrag_t;   // 8 bf16 = 4 VGPRs
typedef __attribute__((ext_vector_type(4))) float facc_t;    // 4 fp32 acc
typedef __attribute__((ext_vector_type(4))) unsigned int u32x4;
typedef __attribute__((ext_vector_type(4))) unsigned short u16x4;

__device__ __forceinline__ float sigmoidf_(float v) { return 1.f / (1.f + __expf(-v)); }

__device__ __forceinline__ unsigned short f2bf(float f) {
    union { float f; unsigned u; } v; v.f = f;
    unsigned r = v.u + 0x7FFFu + ((v.u >> 16) & 1u);   // round-to-nearest-even
    return (unsigned short)(r >> 16);
}
__device__ __forceinline__ float bf2f(unsigned short u) {
    union { unsigned u; float f; } v; v.u = ((unsigned)u) << 16; return v.f;
}
__device__ __forceinline__ unsigned long long pack4(float4 v) {
    return (unsigned long long)f2bf(v.x)
         | ((unsigned long long)f2bf(v.y) << 16)
         | ((unsigned long long)f2bf(v.z) << 32)
         | ((unsigned long long)f2bf(v.w) << 48);
}

// 16B/lane global->LDS DMA. LDS base is wave-uniform; lane L lands at l + L*16B.
__device__ __forceinline__ void stage16(const unsigned short* g, unsigned short* l, int lane) {
#if __has_builtin(__builtin_amdgcn_global_load_lds)
    __builtin_amdgcn_global_load_lds(
        (const __attribute__((address_space(1))) void*)g,
        (__attribute__((address_space(3))) void*)l, 16, 0, 0);
#else
    *(u32x4*)(l + lane * 8) = *(const u32x4*)g;
#endif
}

struct CastArgs {
    const float4* src[3];
    unsigned long long* dst[3];
};

// ---------------------------------------------------------------------------
// PREPROC mega-kernel: one launch fuses four independent memory-bound passes
// (flat-grid partitioned; all 256-thread blocks):
//   logits  : split-K router logits + fused x->bf16 cast
//   cast    : fp32->bf16 cast of 3 shared-weight buffers (16B/8B vectorized)
//   tgu     : transpose+cast gate_w/up_w  [E][C][H] -> [E][H][C], 64x64 tiles
//   tdn     : transpose+cast down_w       [E][H][C] -> [E][C][H], 64x64 tiles
// Transposes use float4 loads (256B/row-segment) + ushort4 stores (128B/group)
// through a [64][65] fp32 LDS tile (both phases 2 lanes/bank = conflict-free).
// ---------------------------------------------------------------------------
#define LG_BLOCKS   ((S / 16) * KSLICES)                    // 1024
#define CAST_BLOCKS (3 * (HS * CDIM / 4 / 256))             // 6144
#define TGU_BLOCKS  (2 * E * (CDIM / 64) * (H / 64))        // 2048
#define TDN_BLOCKS  (E * (H / 64) * (CDIM / 64))            // 1024

__global__ __launch_bounds__(256) void preproc_kernel(
    const float* __restrict__ x, const float* __restrict__ rw,
    float* __restrict__ lgpart, unsigned short* __restrict__ xb,
    CastArgs ca,
    const float* __restrict__ gate_w, unsigned short* __restrict__ gwT,
    const float* __restrict__ up_w,  unsigned short* __restrict__ uwT,
    const float* __restrict__ down_w, unsigned short* __restrict__ dwT)
{
    __shared__ __align__(16) float tbuf[64 * 65];
    const int tid = threadIdx.x;
    int id = blockIdx.x;

    if (id < LG_BLOCKS) {
        // ---- logits + x cast (grid was (S/16=128, KSLICES=8)) ----
        const int ks = id >> 7;
        const int s0 = (id & 127) * 16;
        const int t = tid & 15, e = tid >> 4;
        const float4* xp = (const float4*)(x + (size_t)(s0 + t) * CDIM + ks * (CDIM / KSLICES));
        const float4* wp = (const float4*)(rw + (size_t)e * CDIM + ks * (CDIM / KSLICES));
        float acc = 0.f;
#pragma unroll 8
        for (int c = 0; c < CDIM / KSLICES / 4; ++c) {
            float4 xv = xp[c], wv = wp[c];
            acc += xv.x * wv.x + xv.y * wv.y + xv.z * wv.z + xv.w * wv.w;
        }
        float4 v0 = xp[e * 2], v1 = xp[e * 2 + 1];
        unsigned long long* dst = (unsigned long long*)
            (xb + (size_t)(s0 + t) * CDIM + ks * (CDIM / KSLICES) + e * 8);
        dst[0] = pack4(v0);
        dst[1] = pack4(v1);
        lgpart[((size_t)ks * S + s0 + t) * E + e] = acc;
        return;
    }
    id -= LG_BLOCKS;

    if (id < CAST_BLOCKS) {
        // ---- shared-weight casts (3 bufs x 2048 blocks) ----
        const int buf = id >> 11;
        const int i = (id & 2047) * 256 + tid;
        ca.dst[buf][i] = pack4(ca.src[buf][i]);
        return;
    }
    id -= CAST_BLOCKS;

    // ---- 64x64 vectorized transposes ----
    const float* src; unsigned short* dst; int R, Cc, zz, c0, r0;
    if (id < TGU_BLOCKS) {
        // gate/up: c-tile in [0,4) (H/64), r-tile in [0,16) (CDIM/64), z in [0,32)
        const int bx = id & 3; const int by = (id >> 2) & 15; const int bz = id >> 6;
        R = CDIM; Cc = H;
        src = (bz < E) ? gate_w : up_w;
        dst = (bz < E) ? gwT : uwT;
        zz = (bz < E) ? bz : bz - E;
        c0 = bx * 64; r0 = by * 64;
    } else {
        id -= TGU_BLOCKS;
        // down: c-tile in [0,16) (CDIM/64), r-tile in [0,4) (H/64), z in [0,16)
        const int bx = id & 15; const int by = (id >> 4) & 3; const int bz = id >> 6;
        R = H; Cc = CDIM;
        src = down_w; dst = dwT; zz = bz;
        c0 = bx * 64; r0 = by * 64;
    }
    const size_t mo = (size_t)zz * R * Cc;
    src += mo; dst += mo;
    const int tx = tid & 15, ty = tid >> 4;   // 16 x 16
    // load: 4 rows/thread, float4 each (16 lanes * 16B = 256B contiguous/row)
#pragma unroll
    for (int i = 0; i < 4; ++i) {
        const int row = ty + 16 * i;
        float4 v = *(const float4*)&src[(size_t)(r0 + row) * Cc + c0 + tx * 4];
        float* p = &tbuf[row * 65 + tx * 4];
        p[0] = v.x; p[1] = v.y; p[2] = v.z; p[3] = v.w;   // 2 lanes/bank: free
    }
    __syncthreads();
    // store: out-row c = ty+16j (column of src); 4 r-elems/thread -> ushort4
#pragma unroll
    for (int j = 0; j < 4; ++j) {
        const int c = ty + 16 * j;
        u16x4 o;
#pragma unroll
        for (int i = 0; i < 4; ++i)
            o[i] = f2bf(tbuf[(tx * 4 + i) * 65 + c]);     // 2 lanes/bank: free
        *(u16x4*)&dst[(size_t)(c0 + c) * R + r0 + tx * 4] = o;
    }
}

// ---------------------------------------------------------------------------
// K1b: route one token per thread. Hierarchical compaction:
// LDS histogram -> one global atomicAdd per (block, expert) -> slot writes.
// ---------------------------------------------------------------------------
__global__ __launch_bounds__(256) void route_kernel(
    const float* __restrict__ lgpart, const float* __restrict__ bias,
    int* __restrict__ counts, int* __restrict__ list, float* __restrict__ wlist)
{
    __shared__ int lcount[E];
    __shared__ int lbase[E];
    const int tid = threadIdx.x;
    const int s = blockIdx.x * 256 + tid;
    if (tid < E) lcount[tid] = 0;
    float lgv[E];
#pragma unroll
    for (int i = 0; i < E; ++i) lgv[i] = 0.f;
#pragma unroll
    for (int ks = 0; ks < KSLICES; ++ks) {
        const float4* p = (const float4*)(lgpart + ((size_t)ks * S + s) * E);
#pragma unroll
        for (int q = 0; q < 4; ++q) {
            float4 v = p[q];
            lgv[q * 4 + 0] += v.x; lgv[q * 4 + 1] += v.y;
            lgv[q * 4 + 2] += v.z; lgv[q * 4 + 3] += v.w;
        }
    }
    float sc[E], sb[E];
#pragma unroll
    for (int e2 = 0; e2 < E; ++e2) {
        sc[e2] = 1.f / (1.f + __expf(-lgv[e2]));
        sb[e2] = sc[e2] + bias[e2];
    }
    float gsc[GNUM];
#pragma unroll
    for (int g = 0; g < GNUM; ++g) {
        int b_ = g * EPG;
        int m1 = 0; float v1 = sb[b_];
#pragma unroll
        for (int j = 1; j < EPG; ++j) if (sb[b_ + j] > v1) { v1 = sb[b_ + j]; m1 = j; }
        float v2 = -1e30f;
#pragma unroll
        for (int j = 0; j < EPG; ++j) if (j != m1 && sb[b_ + j] > v2) v2 = sb[b_ + j];
        gsc[g] = v1 + v2;
    }
    int g1 = 0;
#pragma unroll
    for (int g = 1; g < GNUM; ++g) if (gsc[g] > gsc[g1]) g1 = g;
    int g2 = (g1 == 0) ? 1 : 0;
#pragma unroll
    for (int g = 0; g < GNUM; ++g) if (g != g1 && gsc[g] > gsc[g2]) g2 = g;
    bool allowed[E];
#pragma unroll
    for (int e2 = 0; e2 < E; ++e2) {
        int g = e2 >> 2;
        allowed[e2] = (g == g1) || (g == g2);
    }
    int idx[TOPK]; float wk[TOPK];
#pragma unroll
    for (int k = 0; k < TOPK; ++k) {
        int best = 0; float bv = -1e30f;
#pragma unroll
        for (int e2 = 0; e2 < E; ++e2)
            if (allowed[e2] && sb[e2] > bv) { bv = sb[e2]; best = e2; }
        allowed[best] = false;
        idx[k] = best;
        wk[k] = sc[best];
    }
    float inv = 1.f / (wk[0] + wk[1] + wk[2] + wk[3] + 1e-20f);
    __syncthreads();            // lcount zero-init visible
    int lpos[TOPK];
#pragma unroll
    for (int k = 0; k < TOPK; ++k)
        lpos[k] = atomicAdd(&lcount[idx[k]], 1);   // LDS atomic (fast)
    __syncthreads();
    if (tid < E)
        lbase[tid] = atomicAdd(&counts[tid], lcount[tid]);  // 16 global atomics/block
    __syncthreads();
#pragma unroll
    for (int k = 0; k < TOPK; ++k) {
        int ee = idx[k];
        int pos = lbase[ee] + lpos[k];
        list[ee * S + pos] = s | (k << 16);
        wlist[ee * S + pos] = wk[k] * inv;
    }
}

// ---------------------------------------------------------------------------
// m97-style MFMA GEMMs, BK=64 single-buffer (round-2 proven structure):
// two 32-wide k-halves stacked in LDS, 2 barriers per K-step.
// ---------------------------------------------------------------------------

// K4: shared gate+up fused SwiGLU -> shb bf16 [S][HS]. BM=128/BN=64, BK=64.
// grid (HS/64=32, S/128=16).
__global__ __launch_bounds__(256) void gemm_shared_gateup(
    const unsigned short* __restrict__ xb, const unsigned short* __restrict__ gb,
    const unsigned short* __restrict__ ub, unsigned short* __restrict__ shb)
{
    __shared__ __align__(16) unsigned short As[2 * 128 * 32];
    __shared__ __align__(16) unsigned short Bg[2 * 64 * 32];
    __shared__ __align__(16) unsigned short Bu[2 * 64 * 32];
    const int tid = threadIdx.x;
    const int lane = tid & 63, w = tid >> 6;
    const int l15 = lane & 15, q = lane >> 4;
    const int r0 = blockIdx.y * 128;
    const int c0 = blockIdx.x * 64;
    const int wr = (w >> 1) * 64, wc = (w & 1) * 32;
    const int Lrow = lane >> 2;
    const int gseg = (lane & 3) ^ ((lane >> 3) & 3);
    const unsigned short* gA1 = xb + (size_t)(r0 + w * 16 + Lrow) * CDIM + gseg * 8;
    const unsigned short* gA2 = gA1 + (size_t)64 * CDIM;
    const unsigned short* gG  = gb + (size_t)(c0 + w * 16 + Lrow) * CDIM + gseg * 8;
    const unsigned short* gU  = ub + (size_t)(c0 + w * 16 + Lrow) * CDIM + gseg * 8;
    unsigned short* lA1 = &As[(w * 16) * 32];
    unsigned short* lA2 = lA1 + 64 * 32;
    unsigned short* lG  = &Bg[(w * 16) * 32];
    unsigned short* lU  = &Bu[(w * 16) * 32];
    const int swq = (q ^ ((l15 >> 1) & 3)) * 8;
    facc_t accg[4][2], accu[4][2];
#pragma unroll
    for (int i = 0; i < 4; ++i)
#pragma unroll
        for (int j = 0; j < 2; ++j) { accg[i][j] = 0.f; accu[i][j] = 0.f; }
    for (int k0 = 0; k0 < CDIM; k0 += 64) {
        stage16(gA1 + k0,      lA1,             lane);
        stage16(gA1 + k0 + 32, lA1 + 128 * 32,  lane);
        stage16(gA2 + k0,      lA2,             lane);
        stage16(gA2 + k0 + 32, lA2 + 128 * 32,  lane);
        stage16(gG + k0,       lG,              lane);
        stage16(gG + k0 + 32,  lG + 64 * 32,    lane);
        stage16(gU + k0,       lU,              lane);
        stage16(gU + k0 + 32,  lU + 64 * 32,    lane);
        __syncthreads();
#pragma unroll
        for (int kk = 0; kk < 2; ++kk) {
            const unsigned short* Ah = &As[kk * 128 * 32];
            const unsigned short* Gh = &Bg[kk * 64 * 32];
            const unsigned short* Uh = &Bu[kk * 64 * 32];
            bfrag_t af[4], gf[2], uf[2];
#pragma unroll
            for (int i = 0; i < 4; ++i)
                af[i] = *(const bfrag_t*)&Ah[(wr + i * 16 + l15) * 32 + swq];
#pragma unroll
            for (int j = 0; j < 2; ++j) {
                gf[j] = *(const bfrag_t*)&Gh[(wc + j * 16 + l15) * 32 + swq];
                uf[j] = *(const bfrag_t*)&Uh[(wc + j * 16 + l15) * 32 + swq];
            }
#pragma unroll
            for (int i = 0; i < 4; ++i)
#pragma unroll
                for (int j = 0; j < 2; ++j) {
                    accg[i][j] = __builtin_amdgcn_mfma_f32_16x16x32_bf16(af[i], gf[j], accg[i][j], 0, 0, 0);
                    accu[i][j] = __builtin_amdgcn_mfma_f32_16x16x32_bf16(af[i], uf[j], accu[i][j], 0, 0, 0);
                }
        }
        __syncthreads();
    }
#pragma unroll
    for (int i = 0; i < 4; ++i)
#pragma unroll
        for (int j = 0; j < 2; ++j)
#pragma unroll
            for (int r = 0; r < 4; ++r) {
                int row = r0 + wr + i * 16 + q * 4 + r;
                int col = c0 + wc + j * 16 + l15;
                float g = accg[i][j][r], u = accu[i][j][r];
                shb[(size_t)row * HS + col] = f2bf(g * sigmoidf_(g) * u);
            }
}

// K5: shared down-proj + routed-sum epilogue -> out fp32 [S][CDIM].
// BM=64/BN=64, BK=64, K=HS. grid (CDIM/64=16, S/64=32). RUNS LAST.
__global__ __launch_bounds__(256) void gemm_shared_down(
    const unsigned short* __restrict__ shb, const unsigned short* __restrict__ db,
    const unsigned short* __restrict__ dbuf, float* __restrict__ out)
{
    __shared__ __align__(16) unsigned short As[2 * 64 * 32];
    __shared__ __align__(16) unsigned short Bs[2 * 64 * 32];
    const int tid = threadIdx.x;
    const int lane = tid & 63, w = tid >> 6;
    const int l15 = lane & 15, q = lane >> 4;
    const int r0 = blockIdx.y * 64;
    const int c0 = blockIdx.x * 64;
    const int wr = (w >> 1) * 32, wc = (w & 1) * 32;
    const int Lrow = lane >> 2;
    const int gseg = (lane & 3) ^ ((lane >> 3) & 3);
    const unsigned short* gA = shb + (size_t)(r0 + w * 16 + Lrow) * HS + gseg * 8;
    const unsigned short* gB = db + (size_t)(c0 + w * 16 + Lrow) * HS + gseg * 8;
    unsigned short* lA = &As[(w * 16) * 32];
    unsigned short* lB = &Bs[(w * 16) * 32];
    const int swq = (q ^ ((l15 >> 1) & 3)) * 8;
    facc_t acc[2][2];
#pragma unroll
    for (int i = 0; i < 2; ++i)
#pragma unroll
        for (int j = 0; j < 2; ++j) acc[i][j] = 0.f;
    for (int k0 = 0; k0 < HS; k0 += 64) {
        stage16(gA + k0,      lA,            lane);
        stage16(gA + k0 + 32, lA + 64 * 32,  lane);
        stage16(gB + k0,      lB,            lane);
        stage16(gB + k0 + 32, lB + 64 * 32,  lane);
        __syncthreads();
#pragma unroll
        for (int kk = 0; kk < 2; ++kk) {
            const unsigned short* Ah = &As[kk * 64 * 32];
            const unsigned short* Bh = &Bs[kk * 64 * 32];
            bfrag_t af[2], bf[2];
#pragma unroll
            for (int i = 0; i < 2; ++i) af[i] = *(const bfrag_t*)&Ah[(wr + i * 16 + l15) * 32 + swq];
#pragma unroll
            for (int j = 0; j < 2; ++j) bf[j] = *(const bfrag_t*)&Bh[(wc + j * 16 + l15) * 32 + swq];
#pragma unroll
            for (int i = 0; i < 2; ++i)
#pragma unroll
                for (int j = 0; j < 2; ++j)
                    acc[i][j] = __builtin_amdgcn_mfma_f32_16x16x32_bf16(af[i], bf[j], acc[i][j], 0, 0, 0);
        }
        __syncthreads();
    }
#pragma unroll
    for (int i = 0; i < 2; ++i)
#pragma unroll
        for (int j = 0; j < 2; ++j)
#pragma unroll
            for (int r = 0; r < 4; ++r) {
                int row = r0 + wr + i * 16 + q * 4 + r;
                int col = c0 + wc + j * 16 + l15;
                float v = acc[i][j][r];
                const unsigned short* dp = dbuf + ((size_t)row * TOPK) * CDIM + col;
#pragma unroll
                for (int k = 0; k < TOPK; ++k) v += bf2f(dp[(size_t)k * CDIM]);
                out[(size_t)row * CDIM + col] = v;
            }
}

// K6: routed gate+up, gathered A rows, weighted SwiGLU -> hbuf bf16 [S*4][H].
// BM=64/BN=64, BK=64. grid (E, H/64=4, S/64=32); expert-major for XCD L2.
__global__ __launch_bounds__(256) void gemm_routed_gateup(
    const unsigned short* __restrict__ xb, const unsigned short* __restrict__ gwT,
    const unsigned short* __restrict__ uwT, const int* __restrict__ counts,
    const int* __restrict__ list, const float* __restrict__ wlist,
    unsigned short* __restrict__ hbuf)
{
    const int e = blockIdx.x;
    const int n = counts[e];
    const int t0 = blockIdx.z * 64;
    if (t0 >= n) return;
    const int h0 = blockIdx.y * 64;
    __shared__ int toks[64];
    __shared__ int hrw[64];
    __shared__ float wv[64];
    __shared__ __align__(16) unsigned short As[2 * 64 * 32];
    __shared__ __align__(16) unsigned short Bg[2 * 64 * 32];
    __shared__ __align__(16) unsigned short Bu[2 * 64 * 32];
    const int tid = threadIdx.x;
    if (tid < 64) {
        int p = t0 + tid;
        if (p < n) {
            int pk = list[e * S + p];
            toks[tid] = pk & 0xFFFF;
            hrw[tid] = (pk & 0xFFFF) * TOPK + (pk >> 16);
            wv[tid] = wlist[e * S + p];
        } else { toks[tid] = 0; hrw[tid] = 0; wv[tid] = 0.f; }
    }
    __syncthreads();
    const int lane = tid & 63, w = tid >> 6;
    const int l15 = lane & 15, q = lane >> 4;
    const int wr = (w >> 1) * 32, wc = (w & 1) * 32;
    const int Lrow = lane >> 2;
    const int gseg = (lane & 3) ^ ((lane >> 3) & 3);
    const int tokA = toks[w * 16 + Lrow];        // per-lane gathered A row
    const unsigned short* gA = xb + (size_t)tokA * CDIM + gseg * 8;
    const unsigned short* gG = gwT + ((size_t)e * H + h0 + w * 16 + Lrow) * CDIM + gseg * 8;
    const unsigned short* gU = uwT + ((size_t)e * H + h0 + w * 16 + Lrow) * CDIM + gseg * 8;
    unsigned short* lA = &As[(w * 16) * 32];
    unsigned short* lG = &Bg[(w * 16) * 32];
    unsigned short* lU = &Bu[(w * 16) * 32];
    const int swq = (q ^ ((l15 >> 1) & 3)) * 8;
    facc_t accg[2][2], accu[2][2];
#pragma unroll
    for (int i = 0; i < 2; ++i)
#pragma unroll
        for (int j = 0; j < 2; ++j) { accg[i][j] = 0.f; accu[i][j] = 0.f; }
    for (int k0 = 0; k0 < CDIM; k0 += 64) {
        stage16(gA + k0,      lA,            lane);
        stage16(gA + k0 + 32, lA + 64 * 32,  lane);
        stage16(gG + k0,      lG,            lane);
        stage16(gG + k0 + 32, lG + 64 * 32,  lane);
        stage16(gU + k0,      lU,            lane);
        stage16(gU + k0 + 32, lU + 64 * 32,  lane);
        __syncthreads();
#pragma unroll
        for (int kk = 0; kk < 2; ++kk) {
            const unsigned short* Ah = &As[kk * 64 * 32];
            const unsigned short* Gh = &Bg[kk * 64 * 32];
            const unsigned short* Uh = &Bu[kk * 64 * 32];
            bfrag_t af[2], gf[2], uf[2];
#pragma unroll
            for (int i = 0; i < 2; ++i) af[i] = *(const bfrag_t*)&Ah[(wr + i * 16 + l15) * 32 + swq];
#pragma unroll
            for (int j = 0; j < 2; ++j) {
                gf[j] = *(const bfrag_t*)&Gh[(wc + j * 16 + l15) * 32 + swq];
                uf[j] = *(const bfrag_t*)&Uh[(wc + j * 16 + l15) * 32 + swq];
            }
#pragma unroll
            for (int i = 0; i < 2; ++i)
#pragma unroll
                for (int j = 0; j < 2; ++j) {
                    accg[i][j] = __builtin_amdgcn_mfma_f32_16x16x32_bf16(af[i], gf[j], accg[i][j], 0, 0, 0);
                    accu[i][j] = __builtin_amdgcn_mfma_f32_16x16x32_bf16(af[i], uf[j], accu[i][j], 0, 0, 0);
                }
        }
        __syncthreads();
    }
#pragma unroll
    for (int i = 0; i < 2; ++i)
#pragma unroll
        for (int j = 0; j < 2; ++j)
#pragma unroll
            for (int r = 0; r < 4; ++r) {
                int li = wr + i * 16 + q * 4 + r;
                if (t0 + li < n) {
                    int col = h0 + wc + j * 16 + l15;
                    float g = accg[i][j][r], u = accu[i][j][r];
                    hbuf[(size_t)hrw[li] * H + col] = f2bf(wv[li] * g * sigmoidf_(g) * u);
                }
            }
}

// K7: routed down-proj -> dbuf bf16 [S*4][CDIM]. BM=64/BN=64, BK=64, K=H=256.
// grid (E, CDIM/64=16, S/64=32); expert-major for XCD L2.
__global__ __launch_bounds__(256) void gemm_routed_down(
    const unsigned short* __restrict__ hbuf, const unsigned short* __restrict__ dwT,
    const int* __restrict__ counts, const int* __restrict__ list,
    unsigned short* __restrict__ dbuf)
{
    const int e = blockIdx.x;
    const int n = counts[e];
    const int t0 = blockIdx.z * 64;
    if (t0 >= n) return;
    const int c0 = blockIdx.y * 64;
    __shared__ int hrw[64];
    __shared__ __align__(16) unsigned short As[2 * 64 * 32];
    __shared__ __align__(16) unsigned short Bs[2 * 64 * 32];
    const int tid = threadIdx.x;
    if (tid < 64) {
        int p = t0 + tid;
        int pk = (p < n) ? list[e * S + p] : 0;
        hrw[tid] = (pk & 0xFFFF) * TOPK + (pk >> 16);
    }
    __syncthreads();
    const int lane = tid & 63, w = tid >> 6;
    const int l15 = lane & 15, q = lane >> 4;
    const int wr = (w >> 1) * 32, wc = (w & 1) * 32;
    const int Lrow = lane >> 2;
    const int gseg = (lane & 3) ^ ((lane >> 3) & 3);
    const int arow = hrw[w * 16 + Lrow];
    const unsigned short* gA = hbuf + (size_t)arow * H + gseg * 8;
    const unsigned short* gB = dwT + ((size_t)e * CDIM + c0 + w * 16 + Lrow) * H + gseg * 8;
    unsigned short* lA = &As[(w * 16) * 32];
    unsigned short* lB = &Bs[(w * 16) * 32];
    const int swq = (q ^ ((l15 >> 1) & 3)) * 8;
    facc_t acc[2][2];
#pragma unroll
    for (int i = 0; i < 2; ++i)
#pragma unroll
        for (int j = 0; j < 2; ++j) acc[i][j] = 0.f;
    for (int k0 = 0; k0 < H; k0 += 64) {
        stage16(gA + k0,      lA,            lane);
        stage16(gA + k0 + 32, lA + 64 * 32,  lane);
        stage16(gB + k0,      lB,            lane);
        stage16(gB + k0 + 32, lB + 64 * 32,  lane);
        __syncthreads();
#pragma unroll
        for (int kk = 0; kk < 2; ++kk) {
            const unsigned short* Ah = &As[kk * 64 * 32];
            const unsigned short* Bh = &Bs[kk * 64 * 32];
            bfrag_t af[2], bf[2];
#pragma unroll
            for (int i = 0; i < 2; ++i) af[i] = *(const bfrag_t*)&Ah[(wr + i * 16 + l15) * 32 + swq];
#pragma unroll
            for (int j = 0; j < 2; ++j) bf[j] = *(const bfrag_t*)&Bh[(wc + j * 16 + l15) * 32 + swq];
#pragma unroll
            for (int i = 0; i < 2; ++i)
#pragma unroll
                for (int j = 0; j < 2; ++j)
                    acc[i][j] = __builtin_amdgcn_mfma_f32_16x16x32_bf16(af[i], bf[j], acc[i][j], 0, 0, 0);
        }
        __syncthreads();
    }
#pragma unroll
    for (int i = 0; i < 2; ++i)
#pragma unroll
        for (int j = 0; j < 2; ++j)
#pragma unroll
            for (int r = 0; r < 4; ++r) {
                int li = wr + i * 16 + q * 4 + r;
                if (t0 + li < n) {
                    int col = c0 + wc + j * 16 + l15;
                    dbuf[(size_t)hrw[li] * CDIM + col] = f2bf(acc[i][j][r]);
                }
            }
}

// ---------------------------------------------------------------------------
extern "C" void kernel_launch(void* const* d_in, const int* in_sizes, int n_in,
                              void* d_out, int out_size, void* d_ws, size_t ws_size,
                              hipStream_t stream)
{
    const float* x        = (const float*)d_in[0];
    const float* router_w = (const float*)d_in[1];
    const float* bias     = (const float*)d_in[2];
    const float* gate_w   = (const float*)d_in[3];
    const float* up_w     = (const float*)d_in[4];
    const float* down_w   = (const float*)d_in[5];
    const float* sgw      = (const float*)d_in[6];
    const float* suw      = (const float*)d_in[7];
    const float* sdw      = (const float*)d_in[8];
    float* out = (float*)d_out;

    char* ws = (char*)d_ws;
    size_t off = 0;
    int* counts = (int*)(ws + off);            off += 256;
    int* list   = (int*)(ws + off);            off += (size_t)E * S * 4;
    float* wlist = (float*)(ws + off);         off += (size_t)E * S * 4;
    unsigned short* xb  = (unsigned short*)(ws + off); off += (size_t)S * CDIM * 2;
    unsigned short* sgb = (unsigned short*)(ws + off); off += (size_t)HS * CDIM * 2;
    unsigned short* sub = (unsigned short*)(ws + off); off += (size_t)HS * CDIM * 2;
    unsigned short* sdb = (unsigned short*)(ws + off); off += (size_t)CDIM * HS * 2;
    unsigned short* gwT = (unsigned short*)(ws + off); off += (size_t)E * H * CDIM * 2;
    unsigned short* uwT = (unsigned short*)(ws + off); off += (size_t)E * H * CDIM * 2;
    unsigned short* dwT = (unsigned short*)(ws + off); off += (size_t)E * CDIM * H * 2;
    unsigned short* shb = (unsigned short*)(ws + off); off += (size_t)S * HS * 2;
    unsigned short* hbuf = (unsigned short*)(ws + off); off += (size_t)S * TOPK * H * 2;
    unsigned short* dbuf = (unsigned short*)(ws + off); off += (size_t)S * TOPK * CDIM * 2;
    // lgpart (8*S*E floats = 1 MiB) aliases dbuf (consumed by route_kernel
    // before gemm_routed_down writes dbuf; same stream, serial).
    float* lgpart = (float*)dbuf;

    hipMemsetAsync(counts, 0, E * sizeof(int), stream);

    CastArgs ca;
    ca.src[0] = (const float4*)sgw; ca.dst[0] = (unsigned long long*)sgb;
    ca.src[1] = (const float4*)suw; ca.dst[1] = (unsigned long long*)sub;
    ca.src[2] = (const float4*)sdw; ca.dst[2] = (unsigned long long*)sdb;

    // One fused preprocessing launch: logits+xcast, weight casts, transposes.
    preproc_kernel<<<LG_BLOCKS + CAST_BLOCKS + TGU_BLOCKS + TDN_BLOCKS, 256, 0, stream>>>(
        x, router_w, lgpart, xb, ca, gate_w, gwT, up_w, uwT, down_w, dwT);

    route_kernel<<<S / 256, 256, 0, stream>>>(lgpart, bias, counts, list, wlist);

    gemm_shared_gateup<<<dim3(HS / 64, S / 128), 256, 0, stream>>>(xb, sgb, sub, shb);
    gemm_routed_gateup<<<dim3(E, H / 64, S / 64), 256, 0, stream>>>(xb, gwT, uwT, counts, list, wlist, hbuf);
    gemm_routed_down<<<dim3(E, CDIM / 64, S / 64), 256, 0, stream>>>(hbuf, dwT, counts, list, dbuf);
    // LAST: shared down-proj with fused routed-sum epilogue (reads dbuf).
    gemm_shared_down<<<dim3(CDIM / 64, S / 64), 256, 0, stream>>>(shb, sdb, dbuf, out);
}